// Round 1
// baseline (489.768 us; speedup 1.0000x reference)
//
#include <hip/hip_runtime.h>
#include <hip/hip_cooperative_groups.h>

namespace cg = cooperative_groups;

// Problem constants (fixed by reference)
#define BATCH 2
#define NPTS  2048
#define CIN   64
#define COUT  128
#define GD    14                 // padded grid dim: vox in [0,11] -> +1 shift, halo -> [0,13]
#define GD2   (GD*GD)            // 196
#define NCELL (GD*GD*GD)         // 2744
#define M     (BATCH*NPTS)       // 4096
#define VOXF  (BATCH*NCELL*CIN)  // 351232 floats
#define WTEL  (27*COUT*CIN)      // 221184 bf16 elements (transposed weight)
#define GRIDB 512
#define NTHR  (GRIDB*256)        // 131072 threads

typedef __bf16 bf16x8 __attribute__((ext_vector_type(8)));
typedef float  f32x4  __attribute__((ext_vector_type(4)));
typedef unsigned short us8 __attribute__((ext_vector_type(8)));

__device__ __forceinline__ unsigned short f2bf(float f) {
    unsigned u = __builtin_bit_cast(unsigned, f);
    return (unsigned short)((u + 0x7FFFu + ((u >> 16) & 1u)) >> 16);  // RNE
}

// ---------------------------------------------------------------------------
// Shared gemm body: per-lane direct-load MFMA over the 27 stencil offsets.
// Wave = one 16x16 C-tile (16 points x 16 couts), full K=64 per offset.
// No LDS, no __syncthreads: lane l reads exactly its A fragment
// (row = l&15, k = (l>>4)*8 .. +7 and +32) from the bf16 voxel grid.
// 4-deep register prefetch pipeline hides L2 latency.
// ---------------------------------------------------------------------------
__device__ __forceinline__ void gemm_body(int bid, int t,
        const unsigned short* __restrict__ voxbf, const int* __restrict__ cellid,
        const unsigned short* __restrict__ wT, const float* __restrict__ bias,
        float* __restrict__ out) {
    static constexpr int DELTA[27] = {
        -211,-210,-209,-197,-196,-195,-183,-182,-181,
         -15, -14, -13,  -1,   0,   1,  13,  14,  15,
         181, 182, 183, 195, 196, 197, 209, 210, 211 };
    constexpr int PF = 4;

    const int tile = bid & 255;          // same-A pair (tile, half) are 256 apart -> same XCD
    const int half = bid >> 8;
    const int g0   = tile * 16;
    const int b    = g0 >> 11;
    const int l    = t & 63;
    const int w    = t >> 6;
    const int q    = l >> 4;
    const int col  = l & 15;
    const int n0   = half * 64 + w * 16;

    const int cell = cellid[g0 + col];   // A row index == l&15 for this fragment layout
    const unsigned short* arow = voxbf + ((size_t)b*NCELL + cell)*CIN + q*8;
    const unsigned short* wt   = wT + (size_t)(n0 + col)*CIN + q*8;

    us8 av[PF][2];
    us8 bv[PF][2];
    #pragma unroll
    for (int s = 0; s < PF; ++s) {
        const unsigned short* p = arow + DELTA[s]*CIN;
        av[s][0] = *(const us8*)(p);
        av[s][1] = *(const us8*)(p + 32);
        bv[s][0] = *(const us8*)(wt + s*8192);
        bv[s][1] = *(const us8*)(wt + s*8192 + 32);
    }

    f32x4 acc = {0.f, 0.f, 0.f, 0.f};
    #pragma unroll
    for (int oo = 0; oo < 27; ++oo) {
        const int slot = oo % PF;                       // static after full unroll
        us8 a0 = av[slot][0], a1 = av[slot][1];
        us8 b0 = bv[slot][0], b1 = bv[slot][1];
        if (oo + PF < 27) {
            const unsigned short* p = arow + DELTA[oo+PF]*CIN;
            av[slot][0] = *(const us8*)(p);
            av[slot][1] = *(const us8*)(p + 32);
            bv[slot][0] = *(const us8*)(wt + (oo+PF)*8192);
            bv[slot][1] = *(const us8*)(wt + (oo+PF)*8192 + 32);
        }
        acc = __builtin_amdgcn_mfma_f32_16x16x32_bf16(
                  __builtin_bit_cast(bf16x8, a0), __builtin_bit_cast(bf16x8, b0), acc, 0, 0, 0);
        acc = __builtin_amdgcn_mfma_f32_16x16x32_bf16(
                  __builtin_bit_cast(bf16x8, a1), __builtin_bit_cast(bf16x8, b1), acc, 0, 0, 0);
    }

    // epilogue: C/D layout col = lane&15, row = q*4 + reg; out = acc + bias
    const float bs = bias[n0 + col];
    #pragma unroll
    for (int r = 0; r < 4; ++r)
        out[(size_t)(g0 + q*4 + r)*COUT + n0 + col] = acc[r] + bs;
}

// ---------------------------------------------------------------------------
// Fused cooperative kernel: all phases, grid.sync between them.
// ---------------------------------------------------------------------------
__global__ __launch_bounds__(256, 2) void k_fused(
        const float* __restrict__ points, const float* __restrict__ weight,
        const float* __restrict__ feat,   const float* __restrict__ bias,
        float* __restrict__ voxgrid, int* __restrict__ cellid,
        unsigned short* __restrict__ wT, unsigned short* __restrict__ voxbf,
        float* __restrict__ out) {
    cg::grid_group gg = cg::this_grid();
    const int t   = threadIdx.x;
    const int tid = blockIdx.x * 256 + t;

    // phase 1: zero f32 grid, compute padded cell ids, transpose weight -> bf16.
    // Transpose reads coalesced, writes scattered (fire-and-forget, no latency stall).
    for (int i = tid; i < WTEL; i += NTHR) {
        if (i < VOXF/4) ((float4*)voxgrid)[i] = make_float4(0.f, 0.f, 0.f, 0.f);
        if (i < M) {
            const int vx = (int)points[i*3 + 0];
            const int vy = (int)points[i*3 + 1];
            const int vz = (int)points[i*3 + 2];
            cellid[i] = (vx + 1)*GD2 + (vy + 1)*GD + (vz + 1);
        }
        const float wv = weight[i];
        const int off = i >> 13;           // i / 8192
        const int k   = (i >> 7) & 63;     // cin
        const int n   = i & 127;           // cout
        wT[off*8192 + n*64 + k] = f2bf(wv);
    }
    __threadfence(); gg.sync(); __threadfence();

    // phase 2: scatter-add features into the f32 voxel grid.
    for (int i = tid; i < M*CIN; i += NTHR) {
        const int g = i >> 6, ci = i & 63, b = g >> 11;
        atomicAdd(&voxgrid[((size_t)b*NCELL + cellid[g])*CIN + ci], feat[i]);
    }
    __threadfence(); gg.sync(); __threadfence();

    // phase 3: convert the summed grid to bf16 once (RNE, same as before).
    for (int i = tid; i < VOXF/4; i += NTHR) {
        const float4 v = ((const float4*)voxgrid)[i];
        ushort4 pk;
        pk.x = f2bf(v.x); pk.y = f2bf(v.y); pk.z = f2bf(v.z); pk.w = f2bf(v.w);
        ((ushort4*)voxbf)[i] = pk;
    }
    __threadfence(); gg.sync(); __threadfence();

    // phase 4: gather MFMA GEMM.
    gemm_body(blockIdx.x, t, voxbf, cellid, wT, bias, out);
}

// ---------------------------------------------------------------------------
// Fallback path (used only if cooperative launch is rejected): 4 plain kernels.
// ---------------------------------------------------------------------------
__global__ __launch_bounds__(256) void k_init(const float* __restrict__ points,
                                              const float* __restrict__ weight,
                                              float* __restrict__ voxgrid,
                                              int* __restrict__ cellid,
                                              unsigned short* __restrict__ wT) {
    int i = blockIdx.x * 256 + threadIdx.x;
    if (i < VOXF/4) ((float4*)voxgrid)[i] = make_float4(0.f, 0.f, 0.f, 0.f);
    if (i < M) {
        int vx = (int)points[i*3 + 0];
        int vy = (int)points[i*3 + 1];
        int vz = (int)points[i*3 + 2];
        cellid[i] = (vx + 1)*GD2 + (vy + 1)*GD + (vz + 1);
    }
    if (i < WTEL) {
        const float wv = weight[i];
        const int off = i >> 13, k = (i >> 7) & 63, n = i & 127;
        wT[off*8192 + n*64 + k] = f2bf(wv);
    }
}

__global__ __launch_bounds__(256) void k_scatter(const float* __restrict__ feat,
                                                 const int* __restrict__ cellid,
                                                 float* __restrict__ voxgrid) {
    int i = blockIdx.x * 256 + threadIdx.x;
    int g = i >> 6, ci = i & 63, b = g >> 11;
    atomicAdd(&voxgrid[((size_t)b*NCELL + cellid[g])*CIN + ci], feat[i]);
}

__global__ __launch_bounds__(256) void k_cvt(const float* __restrict__ voxgrid,
                                             unsigned short* __restrict__ voxbf) {
    int i = blockIdx.x * 256 + threadIdx.x;
    if (i < VOXF/4) {
        const float4 v = ((const float4*)voxgrid)[i];
        ushort4 pk;
        pk.x = f2bf(v.x); pk.y = f2bf(v.y); pk.z = f2bf(v.z); pk.w = f2bf(v.w);
        ((ushort4*)voxbf)[i] = pk;
    }
}

__global__ __launch_bounds__(256) void k_gemm2(const unsigned short* __restrict__ voxbf,
        const int* __restrict__ cellid, const unsigned short* __restrict__ wT,
        const float* __restrict__ bias, float* __restrict__ out) {
    gemm_body(blockIdx.x, threadIdx.x, voxbf, cellid, wT, bias, out);
}

extern "C" void kernel_launch(void* const* d_in, const int* in_sizes, int n_in,
                              void* d_out, int out_size, void* d_ws, size_t ws_size,
                              hipStream_t stream) {
    (void)in_sizes; (void)n_in; (void)out_size; (void)ws_size;
    const float* points   = (const float*)d_in[0];  // (2,2048,3)
    const float* features = (const float*)d_in[1];  // (2,2048,64)
    const float* weight   = (const float*)d_in[2];  // (3,3,3,64,128)
    const float* bias     = (const float*)d_in[3];  // (128,)
    float* out = (float*)d_out;                     // (2,2048,128)

    char* ws = (char*)d_ws;
    float*          voxgrid = (float*)ws;           ws += (size_t)VOXF*4;   // 1404928 B
    int*            cellid  = (int*)ws;             ws += (size_t)M*4;      //   16384 B
    unsigned short* wTp     = (unsigned short*)ws;  ws += (size_t)WTEL*2;   //  442368 B
    unsigned short* voxbf   = (unsigned short*)ws;                          //  702464 B

    void* args[] = { (void*)&points, (void*)&weight, (void*)&features, (void*)&bias,
                     (void*)&voxgrid, (void*)&cellid, (void*)&wTp, (void*)&voxbf,
                     (void*)&out };
    hipError_t e = hipLaunchCooperativeKernel((const void*)k_fused, dim3(GRIDB), dim3(256),
                                              args, 0, stream);
    if (e != hipSuccess) {
        // Cooperative launch unavailable: equivalent 4-kernel path.
        k_init   <<<(WTEL + 255)/256,    256, 0, stream>>>(points, weight, voxgrid, cellid, wTp);
        k_scatter<<<(M*CIN)/256,         256, 0, stream>>>(features, cellid, voxgrid);
        k_cvt    <<<(VOXF/4 + 255)/256,  256, 0, stream>>>(voxgrid, voxbf);
        k_gemm2  <<<GRIDB,               256, 0, stream>>>(voxbf, cellid, wTp, bias, out);
    }
}

// Round 2
// 103.395 us; speedup vs baseline: 4.7369x; 4.7369x over previous
//
#include <hip/hip_runtime.h>

// Problem constants (fixed by reference)
#define BATCH 2
#define NPTS  2048
#define CIN   64
#define COUT  128
#define GD    14                 // padded grid dim: vox in [0,11] -> +1 shift, halo -> [0,13]
#define GD2   (GD*GD)            // 196
#define NCELL (GD*GD*GD)         // 2744
#define M     (BATCH*NPTS)       // 4096
#define VOXF  (BATCH*NCELL*CIN)  // 351232 floats (1.4 MB, L2-resident)
#define WTEL  (27*COUT*CIN)      // 221184 bf16 elements (transposed weight)

typedef __bf16 bf16x8 __attribute__((ext_vector_type(8)));
typedef float  f32x4  __attribute__((ext_vector_type(4)));
typedef unsigned short us8 __attribute__((ext_vector_type(8)));

__device__ __forceinline__ unsigned short f2bf(float f) {
    unsigned u = __builtin_bit_cast(unsigned, f);
    return (unsigned short)((u + 0x7FFFu + ((u >> 16) & 1u)) >> 16);  // RNE
}

// 8 f32 -> bf16x8 (compiler lowers to RNE cvt_pk; same rounding as f2bf)
__device__ __forceinline__ bf16x8 cvt8(f32x4 lo, f32x4 hi) {
    bf16x8 r;
    r[0] = (__bf16)lo[0]; r[1] = (__bf16)lo[1]; r[2] = (__bf16)lo[2]; r[3] = (__bf16)lo[3];
    r[4] = (__bf16)hi[0]; r[5] = (__bf16)hi[1]; r[6] = (__bf16)hi[2]; r[7] = (__bf16)hi[3];
    return r;
}

// ---------------------------------------------------------------------------
// k_prep: one thread per (point, cin). Every lane recomputes its point's cell
// (wave-uniform: i>>6 constant across the 64-lane wave -> broadcast loads),
// lane cin==0 stores cellid for the gemm, all lanes scatter-add the feature.
// The same threads also transpose the weight (coalesced read, scattered
// fire-and-forget 2B writes into the L2-resident wT).
// Grid must be zeroed beforehand (hipMemsetAsync in kernel_launch).
// ---------------------------------------------------------------------------
__global__ __launch_bounds__(256) void k_prep(const float* __restrict__ points,
                                              const float* __restrict__ feat,
                                              const float* __restrict__ weight,
                                              float* __restrict__ voxgrid,
                                              int* __restrict__ cellid,
                                              unsigned short* __restrict__ wT) {
    const int i   = blockIdx.x * 256 + threadIdx.x;   // [0, M*CIN)
    const int g   = i >> 6;
    const int cin = i & 63;
    const int b   = g >> 11;

    const int vx = (int)points[g*3 + 0];
    const int vy = (int)points[g*3 + 1];
    const int vz = (int)points[g*3 + 2];
    const int cell = (vx + 1)*GD2 + (vy + 1)*GD + (vz + 1);
    if (cin == 0) cellid[g] = cell;
    atomicAdd(&voxgrid[((size_t)b*NCELL + cell)*CIN + cin], feat[i]);

    if (i < WTEL) {
        const int off = i >> 13;        // i / (128*64)
        const int k   = (i >> 7) & 63;  // cin
        const int n   = i & 127;        // cout
        wT[off*8192 + n*64 + k] = f2bf(weight[i]);
    }
}

// ---------------------------------------------------------------------------
// k_gemm: per-lane direct-load MFMA over the 27 stencil offsets.
// Wave = one 16x16 C-tile (16 points x 16 couts), full K=64 per offset.
// No LDS, no __syncthreads: lane l reads exactly its A fragment
// (row = l&15, k = (l>>4)*8..+7 and +32) as f32 from the voxel grid and
// converts in-register. 4-deep register prefetch pipeline hides L2 latency.
// Block pairing: tile = bid&255, half = bid>>8 -> same-A pair 256 apart.
// ---------------------------------------------------------------------------
__global__ __launch_bounds__(256) void k_gemm(const float* __restrict__ voxgrid,
                                              const int* __restrict__ cellid,
                                              const unsigned short* __restrict__ wT,
                                              const float* __restrict__ bias,
                                              float* __restrict__ out) {
    static constexpr int DELTA[27] = {
        -211,-210,-209,-197,-196,-195,-183,-182,-181,
         -15, -14, -13,  -1,   0,   1,  13,  14,  15,
         181, 182, 183, 195, 196, 197, 209, 210, 211 };
    constexpr int PF = 4;

    const int bid  = blockIdx.x;
    const int t    = threadIdx.x;
    const int tile = bid & 255;
    const int half = bid >> 8;
    const int g0   = tile * 16;
    const int b    = g0 >> 11;
    const int l    = t & 63;
    const int w    = t >> 6;
    const int q    = l >> 4;
    const int col  = l & 15;
    const int n0   = half * 64 + w * 16;

    const int cell = cellid[g0 + col];   // A row index == l&15 for this fragment layout
    const float* arow = voxgrid + ((size_t)b*NCELL + cell)*CIN + q*8;
    const unsigned short* wt = wT + (size_t)(n0 + col)*CIN + q*8;

    f32x4 av[PF][4];   // [slot][0:1] = k-chunk q*8, [2:3] = k-chunk q*8+32
    us8   bv[PF][2];
    #pragma unroll
    for (int s = 0; s < PF; ++s) {
        const float* p = arow + DELTA[s]*CIN;
        av[s][0] = *(const f32x4*)(p);
        av[s][1] = *(const f32x4*)(p + 4);
        av[s][2] = *(const f32x4*)(p + 32);
        av[s][3] = *(const f32x4*)(p + 36);
        bv[s][0] = *(const us8*)(wt + s*8192);
        bv[s][1] = *(const us8*)(wt + s*8192 + 32);
    }

    f32x4 acc = {0.f, 0.f, 0.f, 0.f};
    #pragma unroll
    for (int oo = 0; oo < 27; ++oo) {
        const int slot = oo % PF;                       // static after full unroll
        bf16x8 a0 = cvt8(av[slot][0], av[slot][1]);
        bf16x8 a1 = cvt8(av[slot][2], av[slot][3]);
        us8 b0 = bv[slot][0], b1 = bv[slot][1];
        if (oo + PF < 27) {                             // refill this slot
            const float* p = arow + DELTA[oo+PF]*CIN;
            av[slot][0] = *(const f32x4*)(p);
            av[slot][1] = *(const f32x4*)(p + 4);
            av[slot][2] = *(const f32x4*)(p + 32);
            av[slot][3] = *(const f32x4*)(p + 36);
            bv[slot][0] = *(const us8*)(wt + (oo+PF)*8192);
            bv[slot][1] = *(const us8*)(wt + (oo+PF)*8192 + 32);
        }
        acc = __builtin_amdgcn_mfma_f32_16x16x32_bf16(
                  a0, __builtin_bit_cast(bf16x8, b0), acc, 0, 0, 0);
        acc = __builtin_amdgcn_mfma_f32_16x16x32_bf16(
                  a1, __builtin_bit_cast(bf16x8, b1), acc, 0, 0, 0);
    }

    // epilogue: C/D layout col = lane&15, row = q*4 + reg; out = acc + bias
    const float bs = bias[n0 + col];
    #pragma unroll
    for (int r = 0; r < 4; ++r)
        out[(size_t)(g0 + q*4 + r)*COUT + n0 + col] = acc[r] + bs;
}

extern "C" void kernel_launch(void* const* d_in, const int* in_sizes, int n_in,
                              void* d_out, int out_size, void* d_ws, size_t ws_size,
                              hipStream_t stream) {
    (void)in_sizes; (void)n_in; (void)out_size; (void)ws_size;
    const float* points   = (const float*)d_in[0];  // (2,2048,3)
    const float* features = (const float*)d_in[1];  // (2,2048,64)
    const float* weight   = (const float*)d_in[2];  // (3,3,3,64,128)
    const float* bias     = (const float*)d_in[3];  // (128,)
    float* out = (float*)d_out;                     // (2,2048,128)

    char* ws = (char*)d_ws;
    float*          voxgrid = (float*)ws;           ws += (size_t)VOXF*4;   // 1404928 B
    int*            cellid  = (int*)ws;             ws += (size_t)M*4;      //   16384 B
    unsigned short* wTp     = (unsigned short*)ws;                          //  442368 B

    hipMemsetAsync(voxgrid, 0, (size_t)VOXF*4, stream);
    k_prep<<<(M*CIN)/256, 256, 0, stream>>>(points, features, weight, voxgrid, cellid, wTp);
    k_gemm<<<512, 256, 0, stream>>>(voxgrid, cellid, wTp, bias, out);
}